// Round 13
// baseline (1311.928 us; speedup 1.0000x reference)
//
#include <hip/hip_runtime.h>
#include <stdint.h>

#define DIMV 2048
#define SEQV 2048
#define NHV 16
#define HDV 128
#define HIDV 5632
#define NROWS 8192
#define LDP 6144   // packed qkv row stride

typedef short bf16x8 __attribute__((ext_vector_type(8)));
typedef float f32x4 __attribute__((ext_vector_type(4)));
typedef unsigned short u16x8 __attribute__((ext_vector_type(8)));

#define GLD16(src, dst) __builtin_amdgcn_global_load_lds( \
    (const __attribute__((address_space(1))) unsigned int*)(src), \
    (__attribute__((address_space(3))) unsigned int*)(dst), 16, 0, 0)

__device__ __forceinline__ float bf2f(unsigned short u){
  union { unsigned u; float f; } x; x.u = ((unsigned)u) << 16; return x.f;
}
__device__ __forceinline__ unsigned short f2bf(float f){
  union { float f; unsigned u; } x; x.f = f;
  unsigned r = x.u + 0x7fffu + ((x.u >> 16) & 1u);
  return (unsigned short)(r >> 16);
}

// ---------------- transpose + cast: in f32 [R][C] -> out bf16 [C][R] ----------------
__global__ void transpose_cast(const float* __restrict__ in, unsigned short* __restrict__ out,
                               int R, int C){
  __shared__ alignas(16) unsigned short tile[32][33];
  int c0 = blockIdx.x * 32, r0 = blockIdx.y * 32;
  int tx = threadIdx.x, ty = threadIdx.y; // 32 x 8
#pragma unroll
  for (int i = 0; i < 32; i += 8)
    tile[ty + i][tx] = f2bf(in[(long)(r0 + ty + i) * C + (c0 + tx)]);
  __syncthreads();
#pragma unroll
  for (int i = 0; i < 32; i += 8)
    out[(long)(c0 + ty + i) * R + (r0 + tx)] = tile[tx][ty + i];
}

// ---------------- transpose V (bf16): packed[b*S+s][4096 + h*128 + d] -> vt[bh][d][s] ----------------
__global__ void transpose_v(const unsigned short* __restrict__ packed, unsigned short* __restrict__ vt){
  __shared__ alignas(16) unsigned short tile[32][33];
  int bh = blockIdx.z;
  int b = bh >> 4, h = bh & 15;
  int d0 = blockIdx.y * 32, s0 = blockIdx.x * 32;
  int tx = threadIdx.x, ty = threadIdx.y; // 32 x 8
  const unsigned short* src = packed + (long)b * SEQV * LDP + 4096 + (long)h * HDV;
  unsigned short* dst = vt + (long)bh * HDV * SEQV;
#pragma unroll
  for (int i = 0; i < 32; i += 8)
    tile[ty + i][tx] = src[(long)(s0 + ty + i) * LDP + d0 + tx];
  __syncthreads();
#pragma unroll
  for (int i = 0; i < 32; i += 8)
    dst[(long)(d0 + ty + i) * SEQV + s0 + tx] = tile[tx][ty + i];
}

// ---------------- RMSNorm: f32 [8192][2048] -> bf16 ----------------
__global__ __launch_bounds__(256) void rmsnorm_k(const float* __restrict__ x,
                                                 const float* __restrict__ w,
                                                 unsigned short* __restrict__ out){
  int row = blockIdx.x, t = threadIdx.x;
  const float* xr = x + (long)row * DIMV;
  float4 v0 = ((const float4*)xr)[t * 2];
  float4 v1 = ((const float4*)xr)[t * 2 + 1];
  float ss = v0.x*v0.x + v0.y*v0.y + v0.z*v0.z + v0.w*v0.w
           + v1.x*v1.x + v1.y*v1.y + v1.z*v1.z + v1.w*v1.w;
#pragma unroll
  for (int off = 32; off; off >>= 1) ss += __shfl_down(ss, off);
  __shared__ float red[4];
  if ((t & 63) == 0) red[t >> 6] = ss;
  __syncthreads();
  float tot = red[0] + red[1] + red[2] + red[3];
  float sc = rsqrtf(tot * (1.0f / DIMV) + 1e-5f);
  const float* wr = w + t * 8;
  float vv[8] = {v0.x, v0.y, v0.z, v0.w, v1.x, v1.y, v1.z, v1.w};
  u16x8 o;
#pragma unroll
  for (int e = 0; e < 8; e++) o[e] = f2bf(vv[e] * sc * wr[e]);
  *(u16x8*)(out + (long)row * DIMV + t * 8) = o;
}

#define SCHEDB() __builtin_amdgcn_sched_barrier(0)
#define SBAR()   __builtin_amdgcn_s_barrier()

// ======== 256x256 8-phase GEMM (R8-verified), balanced 12/8/4/0 ds_reads, ring {B0,B1,A0,A1}, vmcnt(4) ========
// 512 thr = 8 waves (2M x 4N), per-wave 128x64, BK=64, LDS 128 KB, XOR-swizzled.
// MODE 0: bf16 out. MODE 1: f32 = acc + resid (may alias; thread-local RMW).
// MODE 2: bf16 out with fused RoPE on cols<4096 (q cols<2048 also scaled by 1/sqrt(HD)).
template <int MODE>
__global__ __launch_bounds__(512, 2) void gemm256(const unsigned short* __restrict__ A, int lda,
                                                  const unsigned short* __restrict__ Bt,
                                                  unsigned short* __restrict__ Cb,
                                                  float* __restrict__ Cf,
                                                  const float* __restrict__ resid,
                                                  const float* __restrict__ cosT,
                                                  const float* __restrict__ sinT,
                                                  int ldc, int M, int N, int K){
  __shared__ alignas(16) unsigned short As[2][256 * 64];
  __shared__ alignas(16) unsigned short Bs[2][256 * 64];
  int m0 = blockIdx.y * 256, n0 = blockIdx.x * 256;
  int tid = threadIdx.x, w = tid >> 6, l = tid & 63;
  int wm = w >> 2, wn = w & 3;
  int l15 = l & 15, l4 = l >> 4;
  int sr8 = l >> 3, sl = l & 7;
  int nt = K / 64;

  f32x4 acc[8][4];
#pragma unroll
  for (int i = 0; i < 8; i++)
#pragma unroll
    for (int j = 0; j < 4; j++) acc[i][j] = (f32x4){0.f, 0.f, 0.f, 0.f};

#define GSTAGE(Gp, ld_, r0_, slab) { \
    _Pragma("unroll") \
    for (int r = 0; r < 2; r++){ \
      int row = (r * 8 + w) * 8 + sr8; \
      int cs = sl ^ (row & 7); \
      GLD16((Gp) + (long)((r0_) + row) * (ld_) + cs * 8, (slab) + (r * 8 + w) * 512); \
    } }
#define STAGE_A(tt, half) { int _t = (tt); if (_t < nt) GSTAGE(A + _t * 64, lda, m0 + (half) * 128, &As[_t & 1][(half) * 8192]) }
#define STAGE_B(tt, half) { int _t = (tt); if (_t < nt) GSTAGE(Bt + _t * 64, K, n0 + (half) * 128, &Bs[_t & 1][(half) * 8192]) }
#define LDA8(mi, ks) (*(const bf16x8*)(&As[bi][(wm * 128 + (mi) * 16 + l15) * 64 + (((ks) * 4 + l4) ^ (l15 & 7)) * 8]))
#define LDB8(ni, ks) (*(const bf16x8*)(&Bs[bi][(wn * 64 + (ni) * 16 + l15) * 64 + (((ks) * 4 + l4) ^ (l15 & 7)) * 8]))
#define MFMA4x2(AF, BF, MOFF, NOFF) { \
    _Pragma("unroll") \
    for (int mi = 0; mi < 4; mi++) \
      _Pragma("unroll") \
      for (int ni = 0; ni < 2; ni++) \
        _Pragma("unroll") \
        for (int ks = 0; ks < 2; ks++) \
          acc[mi + (MOFF)][ni + (NOFF)] = __builtin_amdgcn_mfma_f32_16x16x32_bf16(AF[mi][ks], BF[ni][ks], acc[mi + (MOFF)][ni + (NOFF)], 0, 0, 0); }

  // prologue: tile0 all 4 pieces + tile1 A0,A1 (B(1) issued at t=0 P1/P2)
  STAGE_A(0, 0); STAGE_A(0, 1); STAGE_B(0, 0); STAGE_B(0, 1);
  STAGE_A(1, 0); STAGE_A(1, 1);
  asm volatile("s_waitcnt vmcnt(4)" ::: "memory");
  __syncthreads();

  for (int t = 0; t < nt; t++){
    int bi = t & 1;
    bf16x8 a03[4][2], a47[4][2], b01[2][2], b23[2][2];
    // ---- P1: read a03 + b01 (12); stage B0(t+1); MFMA Q1 = a03 x b01
#pragma unroll
    for (int mi = 0; mi < 4; mi++){ a03[mi][0] = LDA8(mi, 0); a03[mi][1] = LDA8(mi, 1); }
#pragma unroll
    for (int ni = 0; ni < 2; ni++){ b01[ni][0] = LDB8(ni, 0); b01[ni][1] = LDB8(ni, 1); }
    STAGE_B(t + 1, 0);
    SBAR();
    asm volatile("s_waitcnt lgkmcnt(0)" ::: "memory");
    SCHEDB();
    __builtin_amdgcn_s_setprio(1);
    MFMA4x2(a03, b01, 0, 0);
    __builtin_amdgcn_s_setprio(0);
    SBAR();
    // ---- P2: read a47 (8); stage B1(t+1); MFMA Q2 = a47 x b01
#pragma unroll
    for (int mi = 0; mi < 4; mi++){ a47[mi][0] = LDA8(mi + 4, 0); a47[mi][1] = LDA8(mi + 4, 1); }
    STAGE_B(t + 1, 1);
    SBAR();
    asm volatile("s_waitcnt lgkmcnt(0)" ::: "memory");
    SCHEDB();
    __builtin_amdgcn_s_setprio(1);
    MFMA4x2(a47, b01, 4, 0);
    __builtin_amdgcn_s_setprio(0);
    SBAR();
    // ---- P3: read b23 (4); stage A0(t+2) (As[bi] reads done at P2); MFMA Q3 = a03 x b23
#pragma unroll
    for (int ni = 0; ni < 2; ni++){ b23[ni][0] = LDB8(ni + 2, 0); b23[ni][1] = LDB8(ni + 2, 1); }
    STAGE_A(t + 2, 0);
    SBAR();
    asm volatile("s_waitcnt lgkmcnt(0)" ::: "memory");
    SCHEDB();
    __builtin_amdgcn_s_setprio(1);
    MFMA4x2(a03, b23, 0, 2);
    __builtin_amdgcn_s_setprio(0);
    SBAR();
    // ---- P4: stage A1(t+2); MFMA Q4 = a47 x b23; counted vmcnt(4)
    STAGE_A(t + 2, 1);
    SBAR();
    __builtin_amdgcn_s_setprio(1);
    MFMA4x2(a47, b23, 4, 2);
    __builtin_amdgcn_s_setprio(0);
    if (t + 2 < nt) asm volatile("s_waitcnt vmcnt(4)" ::: "memory");
    else            asm volatile("s_waitcnt vmcnt(0)" ::: "memory");
    SBAR();
  }
#undef GSTAGE
#undef STAGE_A
#undef STAGE_B
#undef LDA8
#undef LDB8
#undef MFMA4x2

#pragma unroll
  for (int mi = 0; mi < 8; mi++)
#pragma unroll
    for (int ni = 0; ni < 4; ni++)
#pragma unroll
      for (int r = 0; r < 4; r++){
        int row = m0 + wm * 128 + mi * 16 + l4 * 4 + r;
        int col = n0 + wn * 64 + ni * 16 + l15;
        long idx = (long)row * ldc + col;
        float v = acc[mi][ni][r];
        if (MODE == 2){
          // fused RoPE for q/k columns; partner (col^1) lives in lane l^1 at same (mi,ni,r)
          float partner = __shfl_xor(v, 1);
          if (col < 4096){
            int ii = (col & 127) >> 1;
            int s  = row & (SEQV - 1);
            float c = cosT[s * 64 + ii], sn = sinT[s * 64 + ii];
            bool odd = (col & 1);
            float a = odd ? partner : v;
            float b = odd ? v : partner;
            float out = odd ? (a * sn + b * c) : (a * c - b * sn);
            if (col < 2048) out *= 0.08838834764831845f;
            v = out;
          }
        }
        if (MODE == 1) Cf[idx] = v + resid[idx];
        else           Cb[idx] = f2bf(v);
      }
}

// ======== fused FFN13, balanced phases (256m x 128n): G = silu(A@W1t^T) * (A@W3t^T) ========
__global__ __launch_bounds__(512, 2) void ffn13_256(const unsigned short* __restrict__ A,
                                                    const unsigned short* __restrict__ B1t,
                                                    const unsigned short* __restrict__ B3t,
                                                    unsigned short* __restrict__ G,
                                                    int M, int N, int K){
  __shared__ alignas(16) unsigned short As[2][256 * 64];
  __shared__ alignas(16) unsigned short B1s[2][128 * 64];
  __shared__ alignas(16) unsigned short B3s[2][128 * 64];
  int m0 = blockIdx.y * 256, n0 = blockIdx.x * 128;
  int tid = threadIdx.x, w = tid >> 6, l = tid & 63;
  int wm = w >> 2, wn = w & 3;   // wave tile: 128m x 32n
  int l15 = l & 15, l4 = l >> 4;
  int sr8 = l >> 3, sl = l & 7;
  int nt = K / 64;

  f32x4 acc1[8][2], acc3[8][2];
#pragma unroll
  for (int i = 0; i < 8; i++)
#pragma unroll
    for (int j = 0; j < 2; j++){ acc1[i][j] = (f32x4){0.f,0.f,0.f,0.f}; acc3[i][j] = (f32x4){0.f,0.f,0.f,0.f}; }

#define GSTAGE(Gp, ld_, r0_, slab) { \
    _Pragma("unroll") \
    for (int r = 0; r < 2; r++){ \
      int row = (r * 8 + w) * 8 + sr8; \
      int cs = sl ^ (row & 7); \
      GLD16((Gp) + (long)((r0_) + row) * (ld_) + cs * 8, (slab) + (r * 8 + w) * 512); \
    } }
#define STAGE_A(tt, half) { int _t = (tt); if (_t < nt) GSTAGE(A + _t * 64, K, m0 + (half) * 128, &As[_t & 1][(half) * 8192]) }
#define STAGE_B1(tt) { int _t = (tt); if (_t < nt) GSTAGE(B1t + _t * 64, K, n0, &B1s[_t & 1][0]) }
#define STAGE_B3(tt) { int _t = (tt); if (_t < nt) GSTAGE(B3t + _t * 64, K, n0, &B3s[_t & 1][0]) }
#define LDA8(mi, ks) (*(const bf16x8*)(&As[bi][(wm * 128 + (mi) * 16 + l15) * 64 + (((ks) * 4 + l4) ^ (l15 & 7)) * 8]))
#define LDB18(ni, ks) (*(const bf16x8*)(&B1s[bi][(wn * 32 + (ni) * 16 + l15) * 64 + (((ks) * 4 + l4) ^ (l15 & 7)) * 8]))
#define LDB38(ni, ks) (*(const bf16x8*)(&B3s[bi][(wn * 32 + (ni) * 16 + l15) * 64 + (((ks) * 4 + l4) ^ (l15 & 7)) * 8]))
#define MFMA4x2(AF, BF, ACC, MOFF) { \
    _Pragma("unroll") \
    for (int mi = 0; mi < 4; mi++) \
      _Pragma("unroll") \
      for (int ni = 0; ni < 2; ni++) \
        _Pragma("unroll") \
        for (int ks = 0; ks < 2; ks++) \
          ACC[mi + (MOFF)][ni] = __builtin_amdgcn_mfma_f32_16x16x32_bf16(AF[mi][ks], BF[ni][ks], ACC[mi + (MOFF)][ni], 0, 0, 0); }

  // prologue: tile0 all pieces + tile1 A0,A1 (B1(1)/B3(1) issued at t=0 P1/P2)
  STAGE_A(0, 0); STAGE_A(0, 1); STAGE_B1(0); STAGE_B3(0);
  STAGE_A(1, 0); STAGE_A(1, 1);
  asm volatile("s_waitcnt vmcnt(4)" ::: "memory");
  __syncthreads();

  for (int t = 0; t < nt; t++){
    int bi = t & 1;
    bf16x8 a03[4][2], a47[4][2], b1f[2][2], b3f[2][2];
    // ---- P1: read a03 + b1f (12); stage B1(t+1); MFMA acc1 mi0-3
#pragma unroll
    for (int mi = 0; mi < 4; mi++){ a03[mi][0] = LDA8(mi, 0); a03[mi][1] = LDA8(mi, 1); }
#pragma unroll
    for (int ni = 0; ni < 2; ni++){ b1f[ni][0] = LDB18(ni, 0); b1f[ni][1] = LDB18(ni, 1); }
    STAGE_B1(t + 1);
    SBAR();
    asm volatile("s_waitcnt lgkmcnt(0)" ::: "memory");
    SCHEDB();
    __builtin_amdgcn_s_setprio(1);
    MFMA4x2(a03, b1f, acc1, 0);
    __builtin_amdgcn_s_setprio(0);
    SBAR();
    // ---- P2: read a47 (8); stage B3(t+1); MFMA acc1 mi4-7
#pragma unroll
    for (int mi = 0; mi < 4; mi++){ a47[mi][0] = LDA8(mi + 4, 0); a47[mi][1] = LDA8(mi + 4, 1); }
    STAGE_B3(t + 1);
    SBAR();
    asm volatile("s_waitcnt lgkmcnt(0)" ::: "memory");
    SCHEDB();
    __builtin_amdgcn_s_setprio(1);
    MFMA4x2(a47, b1f, acc1, 4);
    __builtin_amdgcn_s_setprio(0);
    SBAR();
    // ---- P3: read b3f (4); stage A0(t+2) (As[bi] reads done at P2); MFMA acc3 mi0-3
#pragma unroll
    for (int ni = 0; ni < 2; ni++){ b3f[ni][0] = LDB38(ni, 0); b3f[ni][1] = LDB38(ni, 1); }
    STAGE_A(t + 2, 0);
    SBAR();
    asm volatile("s_waitcnt lgkmcnt(0)" ::: "memory");
    SCHEDB();
    __builtin_amdgcn_s_setprio(1);
    MFMA4x2(a03, b3f, acc3, 0);
    __builtin_amdgcn_s_setprio(0);
    SBAR();
    // ---- P4: stage A1(t+2); MFMA acc3 mi4-7; counted vmcnt(4)
    STAGE_A(t + 2, 1);
    SBAR();
    __builtin_amdgcn_s_setprio(1);
    MFMA4x2(a47, b3f, acc3, 4);
    __builtin_amdgcn_s_setprio(0);
    if (t + 2 < nt) asm volatile("s_waitcnt vmcnt(4)" ::: "memory");
    else            asm volatile("s_waitcnt vmcnt(0)" ::: "memory");
    SBAR();
  }
#undef GSTAGE
#undef STAGE_A
#undef STAGE_B1
#undef STAGE_B3
#undef LDA8
#undef LDB18
#undef LDB38
#undef MFMA4x2

#pragma unroll
  for (int mi = 0; mi < 8; mi++)
#pragma unroll
    for (int ni = 0; ni < 2; ni++)
#pragma unroll
      for (int r = 0; r < 4; r++){
        int row = m0 + wm * 128 + mi * 16 + l4 * 4 + r;
        int col = n0 + wn * 32 + ni * 16 + l15;
        float a = acc1[mi][ni][r];
        float si = a * (1.f / (1.f + __expf(-a)));
        G[(long)row * N + col] = f2bf(si * acc3[mi][ni][r]);
      }
}

// ---------------- Flash attention (causal), 8 waves / 128 q-rows, dbuf, XOR-swizzled LDS ----------------
// packed: q cols [0,2048), k cols [2048,4096); o over q region. vt: [64 bh][128 d][2048 s].
__global__ __launch_bounds__(512) void attn_k(unsigned short* __restrict__ p,
                                              const unsigned short* __restrict__ vt){
  __shared__ alignas(16) unsigned short Ks[2][64 * 128]; // [key][d], slot ^= key&7
  __shared__ alignas(16) unsigned short Vs[2][128 * 64]; // [d][key], slot ^= d&7
  __shared__ alignas(16) unsigned short Ps[8][16 * 64];  // per-wave [qr][key], swizzled
  int qt = (gridDim.x - 1) - blockIdx.x;  // reversed: big blocks first
  int bh = blockIdx.y;
  int b = bh >> 4, h = bh & 15;
  int tid = threadIdx.x, w = tid >> 6, l = tid & 63;
  int l15 = l & 15, l4 = l >> 4;
  int qrow0 = qt * 128 + w * 16;
  long baseQ = (long)b * SEQV * LDP + (long)h * HDV;
  long baseV = (long)bh * HDV * SEQV;

  bf16x8 qf[4];
#pragma unroll
  for (int dc = 0; dc < 4; dc++)
    qf[dc] = *(const bf16x8*)(p + baseQ + (long)(qrow0 + l15) * LDP + dc * 32 + l4 * 8);

  f32x4 acc[8];
#pragma unroll
  for (int df = 0; df < 8; df++) acc[df] = (f32x4){0.f, 0.f, 0.f, 0.f};
  float mOld[4], lsum[4];
#pragma unroll
  for (int r = 0; r < 4; r++){ mOld[r] = -1e30f; lsum[r] = 0.f; }

  // 8 waves share staging: wave w stages K rows [w*8, w*8+8) and V rows [w*16, w*16+16)
#define ATTN_STAGE(buf, kt) {                                                       \
    int k0 = (kt) * 64;                                                             \
    _Pragma("unroll")                                                               \
    for (int i = 0; i < 2; i++){                                                    \
      int row = w * 8 + i * 4 + (l >> 4);                                           \
      int slot = (l & 15) ^ (row & 7);                                              \
      GLD16(p + baseQ + 2048 + (long)(k0 + row) * LDP + slot * 8,                   \
            Ks[buf] + (w * 8 + i * 4) * 128);                                       \
    }                                                                               \
    _Pragma("unroll")                                                               \
    for (int i = 0; i < 2; i++){                                                    \
      int row = w * 16 + i * 8 + (l >> 3);                                          \
      int slot = (l & 7) ^ (row & 7);                                               \
      GLD16(vt + baseV + (long)row * SEQV + k0 + slot * 8,                          \
            Vs[buf] + (w * 16 + i * 8) * 64);                                       \
    } }

  int ntile = 2 * (qt + 1);
  ATTN_STAGE(0, 0);
  asm volatile("s_waitcnt vmcnt(0)" ::: "memory");
  __syncthreads();
  int cur = 0;
  for (int tki = 0; tki < ntile; tki++){
    int k0 = tki * 64;
    if (tki + 1 < ntile) ATTN_STAGE(cur ^ 1, tki + 1);

    float s[4][4];
    __builtin_amdgcn_s_setprio(1);
#pragma unroll
    for (int kf = 0; kf < 4; kf++){
      f32x4 sf = (f32x4){0.f, 0.f, 0.f, 0.f};
#pragma unroll
      for (int dc = 0; dc < 4; dc++){
        bf16x8 kb = *(const bf16x8*)(Ks[cur] + (kf * 16 + l15) * 128 + (((dc * 4 + l4) ^ (l15 & 7)) * 8));
        sf = __builtin_amdgcn_mfma_f32_16x16x32_bf16(qf[dc], kb, sf, 0, 0, 0);
      }
      int key = k0 + kf * 16 + l15;
#pragma unroll
      for (int r = 0; r < 4; r++){
        int rowi = qrow0 + l4 * 4 + r;
        s[kf][r] = (key <= rowi) ? sf[r] : -1e30f;
      }
    }
    __builtin_amdgcn_s_setprio(0);
    float scale[4];
#pragma unroll
    for (int r = 0; r < 4; r++){
      float vmax = fmaxf(fmaxf(s[0][r], s[1][r]), fmaxf(s[2][r], s[3][r]));
      for (int mm = 8; mm; mm >>= 1) vmax = fmaxf(vmax, __shfl_xor(vmax, mm));
      float mNew = fmaxf(mOld[r], vmax);
      scale[r] = __expf(mOld[r] - mNew);
      float ps = 0.f;
#pragma unroll
      for (int kf = 0; kf < 4; kf++){
        float pp = __expf(s[kf][r] - mNew);
        s[kf][r] = pp;
        ps += pp;
      }
      for (int mm = 8; mm; mm >>= 1) ps += __shfl_xor(ps, mm);
      lsum[r] = lsum[r] * scale[r] + ps;
      mOld[r] = mNew;
    }
#pragma unroll
    for (int df = 0; df < 8; df++)
#pragma unroll
      for (int r = 0; r < 4; r++) acc[df][r] *= scale[r];
#pragma unroll
    for (int kf = 0; kf < 4; kf++)
#pragma unroll
      for (int r = 0; r < 4; r++){
        int row = l4 * 4 + r;
        int sidx = row * 64 + (((((kf * 16 + l15) * 2)) ^ ((row & 7) << 4)) >> 1);
        Ps[w][sidx] = f2bf(s[kf][r]);
      }
    __builtin_amdgcn_s_setprio(1);
#pragma unroll
    for (int kc = 0; kc < 2; kc++){
      bf16x8 pa = *(const bf16x8*)(Ps[w] + l15 * 64 + (((kc * 64 + l4 * 16) ^ ((l15 & 7) << 4)) >> 1));
#pragma unroll
      for (int df = 0; df < 8; df++){
        bf16x8 vb = *(const bf16x8*)(Vs[cur] + (df * 16 + l15) * 64 + (((kc * 4 + l4) ^ (l15 & 7)) * 8));
        acc[df] = __builtin_amdgcn_mfma_f32_16x16x32_bf16(pa, vb, acc[df], 0, 0, 0);
      }
    }
    __builtin_amdgcn_s_setprio(0);
    asm volatile("s_waitcnt vmcnt(0)" ::: "memory");
    __syncthreads();
    cur ^= 1;
  }
#pragma unroll
  for (int df = 0; df < 8; df++)
#pragma unroll
    for (int r = 0; r < 4; r++){
      int rows = qrow0 + l4 * 4 + r;
      p[baseQ + (long)rows * LDP + df * 16 + l15] = f2bf(acc[df][r] / lsum[r]);
    }
#undef ATTN_STAGE
}

extern "C" void kernel_launch(void* const* d_in, const int* in_sizes, int n_in,
                              void* d_out, int out_size, void* d_ws, size_t ws_size,
                              hipStream_t stream){
  const float* x    = (const float*)d_in[0];
  const float* wq   = (const float*)d_in[1];
  const float* wk   = (const float*)d_in[2];
  const float* wv   = (const float*)d_in[3];
  const float* wo   = (const float*)d_in[4];
  const float* w1   = (const float*)d_in[5];
  const float* w2   = (const float*)d_in[6]; // (HID, DIM)
  const float* w3   = (const float*)d_in[7];
  const float* anw  = (const float*)d_in[8];
  const float* fnw  = (const float*)d_in[9];
  const float* fcos = (const float*)d_in[10];
  const float* fsin = (const float*)d_in[11];

  char* ws = (char*)d_ws;
  size_t off = 0;
  auto alloc = [&](size_t bytes) -> void* {
    void* p = ws + off;
    off += (bytes + 255) & ~(size_t)255;
    return p;
  };
  const size_t SQ = (size_t)DIMV * DIMV * 2;      // 8 MB
  const size_t SW = (size_t)DIMV * HIDV * 2;      // 22 MB
  const size_t SA = (size_t)NROWS * DIMV * 2;     // 32 MB
  const size_t SP = (size_t)NROWS * LDP * 2;      // 96 MB packed qkv

  unsigned short* wqT = (unsigned short*)alloc(SQ);   // wqT|wkT|wvT contiguous: Bt rows 0..6143
  unsigned short* wkT = (unsigned short*)alloc(SQ);
  unsigned short* wvT = (unsigned short*)alloc(SQ);
  unsigned short* woT = (unsigned short*)alloc(SQ);
  unsigned short* w1T = (unsigned short*)alloc(SW);
  unsigned short* w3T = (unsigned short*)alloc(SW);
  unsigned short* w2T = (unsigned short*)alloc(SW);
  unsigned short* hn  = (unsigned short*)alloc(SA);   // attn-norm; reused as vt during attn; rewritten as ffn-norm
  unsigned short* pk  = (unsigned short*)alloc(SP);   // packed [row][q|k|v]; later reused as g
  unsigned short* vtb = hn;                           // vt[64 bh][128 d][2048 s] == 32 MB
  unsigned short* g   = pk;                           // FFN gate (88 MB) reuses packed (96 MB)
  float* hf = (float*)d_out;                          // h = x + attn (f32) lives in d_out
  (void)ws_size; (void)in_sizes; (void)n_in; (void)out_size;
  (void)wkT; (void)wvT;

  dim3 tb(32, 8);
  transpose_cast<<<dim3(DIMV/32, DIMV/32), tb, 0, stream>>>(wq, wqT, DIMV, DIMV);
  transpose_cast<<<dim3(DIMV/32, DIMV/32), tb, 0, stream>>>(wk, wkT, DIMV, DIMV);
  transpose_cast<<<dim3(DIMV/32, DIMV/32), tb, 0, stream>>>(wv, wvT, DIMV, DIMV);
  transpose_cast<<<dim3(DIMV/32, DIMV/32), tb, 0, stream>>>(wo, woT, DIMV, DIMV);
  transpose_cast<<<dim3(HIDV/32, DIMV/32), tb, 0, stream>>>(w1, w1T, DIMV, HIDV);
  transpose_cast<<<dim3(HIDV/32, DIMV/32), tb, 0, stream>>>(w3, w3T, DIMV, HIDV);
  transpose_cast<<<dim3(DIMV/32, HIDV/32), tb, 0, stream>>>(w2, w2T, HIDV, DIMV);

  rmsnorm_k<<<NROWS, 256, 0, stream>>>(x, anw, hn);

  // fused QKV + RoPE: packed[row][6144] = rope(hn @ [wq|wk|wv])
  gemm256<2><<<dim3(LDP/256, NROWS/256), 512, 0, stream>>>(hn, DIMV, wqT, pk, nullptr, nullptr, fcos, fsin, LDP, NROWS, LDP, DIMV);

  transpose_v<<<dim3(SEQV/32, HDV/32, 4 * NHV), tb, 0, stream>>>(pk, vtb);

  attn_k<<<dim3(SEQV/128, 4 * NHV), 512, 0, stream>>>(pk, vtb);

  // h = attn @ wo + x
  gemm256<1><<<dim3(DIMV/256, NROWS/256), 512, 0, stream>>>(pk, LDP, woT, nullptr, hf, x, nullptr, nullptr, DIMV, NROWS, DIMV, DIMV);

  rmsnorm_k<<<NROWS, 256, 0, stream>>>(hf, fnw, hn);

  ffn13_256<<<dim3(HIDV/128, NROWS/256), 512, 0, stream>>>(hn, w1T, w3T, g, NROWS, HIDV, DIMV);

  gemm256<1><<<dim3(DIMV/256, NROWS/256), 512, 0, stream>>>(g, HIDV, w2T, nullptr, hf, (const float*)hf, nullptr, nullptr, DIMV, NROWS, DIMV, HIDV);
}

// Round 14
// 1248.993 us; speedup vs baseline: 1.0504x; 1.0504x over previous
//
#include <hip/hip_runtime.h>
#include <stdint.h>

#define DIMV 2048
#define SEQV 2048
#define NHV 16
#define HDV 128
#define HIDV 5632
#define NROWS 8192
#define LDP 6144   // packed qkv row stride

typedef short bf16x8 __attribute__((ext_vector_type(8)));
typedef float f32x4 __attribute__((ext_vector_type(4)));
typedef unsigned short u16x8 __attribute__((ext_vector_type(8)));

#define GLD16(src, dst) __builtin_amdgcn_global_load_lds( \
    (const __attribute__((address_space(1))) unsigned int*)(src), \
    (__attribute__((address_space(3))) unsigned int*)(dst), 16, 0, 0)

__device__ __forceinline__ float bf2f(unsigned short u){
  union { unsigned u; float f; } x; x.u = ((unsigned)u) << 16; return x.f;
}
__device__ __forceinline__ unsigned short f2bf(float f){
  union { float f; unsigned u; } x; x.f = f;
  unsigned r = x.u + 0x7fffu + ((x.u >> 16) & 1u);
  return (unsigned short)(r >> 16);
}

// ---------------- transpose + cast, multi-weight: in f32 [R][C] -> out bf16 [C][R] ----------------
// up to 4 (src,dst) pairs selected by blockIdx.z; all pairs share R,C.
__global__ void transpose_cast4(const float* s0, const float* s1, const float* s2, const float* s3,
                                unsigned short* d0g, unsigned short* d1g, unsigned short* d2g, unsigned short* d3g,
                                int R, int C){
  __shared__ alignas(16) unsigned short tile[32][33];
  const float* in; unsigned short* out;
  switch (blockIdx.z){
    case 0: in = s0; out = d0g; break;
    case 1: in = s1; out = d1g; break;
    case 2: in = s2; out = d2g; break;
    default: in = s3; out = d3g; break;
  }
  int c0 = blockIdx.x * 32, r0 = blockIdx.y * 32;
  int tx = threadIdx.x, ty = threadIdx.y; // 32 x 8
#pragma unroll
  for (int i = 0; i < 32; i += 8)
    tile[ty + i][tx] = f2bf(in[(long)(r0 + ty + i) * C + (c0 + tx)]);
  __syncthreads();
#pragma unroll
  for (int i = 0; i < 32; i += 8)
    out[(long)(c0 + ty + i) * R + (r0 + tx)] = tile[tx][ty + i];
}

// ---------------- transpose V (bf16): packed[b*S+s][4096 + h*128 + d] -> vt[bh][d][s] ----------------
__global__ void transpose_v(const unsigned short* __restrict__ packed, unsigned short* __restrict__ vt){
  __shared__ alignas(16) unsigned short tile[32][33];
  int bh = blockIdx.z;
  int b = bh >> 4, h = bh & 15;
  int d0 = blockIdx.y * 32, s0 = blockIdx.x * 32;
  int tx = threadIdx.x, ty = threadIdx.y; // 32 x 8
  const unsigned short* src = packed + (long)b * SEQV * LDP + 4096 + (long)h * HDV;
  unsigned short* dst = vt + (long)bh * HDV * SEQV;
#pragma unroll
  for (int i = 0; i < 32; i += 8)
    tile[ty + i][tx] = src[(long)(s0 + ty + i) * LDP + d0 + tx];
  __syncthreads();
#pragma unroll
  for (int i = 0; i < 32; i += 8)
    dst[(long)(d0 + ty + i) * SEQV + s0 + tx] = tile[tx][ty + i];
}

// ---------------- RMSNorm: f32 [8192][2048] -> bf16 ----------------
__global__ __launch_bounds__(256) void rmsnorm_k(const float* __restrict__ x,
                                                 const float* __restrict__ w,
                                                 unsigned short* __restrict__ out){
  int row = blockIdx.x, t = threadIdx.x;
  const float* xr = x + (long)row * DIMV;
  float4 v0 = ((const float4*)xr)[t * 2];
  float4 v1 = ((const float4*)xr)[t * 2 + 1];
  float ss = v0.x*v0.x + v0.y*v0.y + v0.z*v0.z + v0.w*v0.w
           + v1.x*v1.x + v1.y*v1.y + v1.z*v1.z + v1.w*v1.w;
#pragma unroll
  for (int off = 32; off; off >>= 1) ss += __shfl_down(ss, off);
  __shared__ float red[4];
  if ((t & 63) == 0) red[t >> 6] = ss;
  __syncthreads();
  float tot = red[0] + red[1] + red[2] + red[3];
  float sc = rsqrtf(tot * (1.0f / DIMV) + 1e-5f);
  const float* wr = w + t * 8;
  float vv[8] = {v0.x, v0.y, v0.z, v0.w, v1.x, v1.y, v1.z, v1.w};
  u16x8 o;
#pragma unroll
  for (int e = 0; e < 8; e++) o[e] = f2bf(vv[e] * sc * wr[e]);
  *(u16x8*)(out + (long)row * DIMV + t * 8) = o;
}

#define SCHEDB() __builtin_amdgcn_sched_barrier(0)
#define SBAR()   __builtin_amdgcn_s_barrier()

// ======== 256x256 8-phase GEMM (R8-verified), balanced 12/8/4/0 ds_reads, ring {B0,B1,A0,A1}, vmcnt(4) ========
// 512 thr = 8 waves (2M x 4N), per-wave 128x64, BK=64, LDS 128 KB, XOR-swizzled.
// MODE 0: bf16 out. MODE 1: f32 = acc + resid (may alias; thread-local RMW).
template <int MODE>
__global__ __launch_bounds__(512, 2) void gemm256(const unsigned short* __restrict__ A, int lda,
                                                  const unsigned short* __restrict__ Bt,
                                                  unsigned short* __restrict__ Cb,
                                                  float* __restrict__ Cf,
                                                  const float* __restrict__ resid,
                                                  int ldc, int M, int N, int K){
  __shared__ alignas(16) unsigned short As[2][256 * 64];
  __shared__ alignas(16) unsigned short Bs[2][256 * 64];
  int m0 = blockIdx.y * 256, n0 = blockIdx.x * 256;
  int tid = threadIdx.x, w = tid >> 6, l = tid & 63;
  int wm = w >> 2, wn = w & 3;
  int l15 = l & 15, l4 = l >> 4;
  int sr8 = l >> 3, sl = l & 7;
  int nt = K / 64;

  f32x4 acc[8][4];
#pragma unroll
  for (int i = 0; i < 8; i++)
#pragma unroll
    for (int j = 0; j < 4; j++) acc[i][j] = (f32x4){0.f, 0.f, 0.f, 0.f};

#define GSTAGE(Gp, ld_, r0_, slab) { \
    _Pragma("unroll") \
    for (int r = 0; r < 2; r++){ \
      int row = (r * 8 + w) * 8 + sr8; \
      int cs = sl ^ (row & 7); \
      GLD16((Gp) + (long)((r0_) + row) * (ld_) + cs * 8, (slab) + (r * 8 + w) * 512); \
    } }
#define STAGE_A(tt, half) { int _t = (tt); if (_t < nt) GSTAGE(A + _t * 64, lda, m0 + (half) * 128, &As[_t & 1][(half) * 8192]) }
#define STAGE_B(tt, half) { int _t = (tt); if (_t < nt) GSTAGE(Bt + _t * 64, K, n0 + (half) * 128, &Bs[_t & 1][(half) * 8192]) }
#define LDA8(mi, ks) (*(const bf16x8*)(&As[bi][(wm * 128 + (mi) * 16 + l15) * 64 + (((ks) * 4 + l4) ^ (l15 & 7)) * 8]))
#define LDB8(ni, ks) (*(const bf16x8*)(&Bs[bi][(wn * 64 + (ni) * 16 + l15) * 64 + (((ks) * 4 + l4) ^ (l15 & 7)) * 8]))
#define MFMA4x2(AF, BF, MOFF, NOFF) { \
    _Pragma("unroll") \
    for (int mi = 0; mi < 4; mi++) \
      _Pragma("unroll") \
      for (int ni = 0; ni < 2; ni++) \
        _Pragma("unroll") \
        for (int ks = 0; ks < 2; ks++) \
          acc[mi + (MOFF)][ni + (NOFF)] = __builtin_amdgcn_mfma_f32_16x16x32_bf16(AF[mi][ks], BF[ni][ks], acc[mi + (MOFF)][ni + (NOFF)], 0, 0, 0); }

  // prologue: tile0 all 4 pieces + tile1 A0,A1 (B(1) issued at t=0 P1/P2)
  STAGE_A(0, 0); STAGE_A(0, 1); STAGE_B(0, 0); STAGE_B(0, 1);
  STAGE_A(1, 0); STAGE_A(1, 1);
  asm volatile("s_waitcnt vmcnt(4)" ::: "memory");
  __syncthreads();

  for (int t = 0; t < nt; t++){
    int bi = t & 1;
    bf16x8 a03[4][2], a47[4][2], b01[2][2], b23[2][2];
    // ---- P1: read a03 + b01 (12); stage B0(t+1); MFMA Q1 = a03 x b01
#pragma unroll
    for (int mi = 0; mi < 4; mi++){ a03[mi][0] = LDA8(mi, 0); a03[mi][1] = LDA8(mi, 1); }
#pragma unroll
    for (int ni = 0; ni < 2; ni++){ b01[ni][0] = LDB8(ni, 0); b01[ni][1] = LDB8(ni, 1); }
    STAGE_B(t + 1, 0);
    SBAR();
    asm volatile("s_waitcnt lgkmcnt(0)" ::: "memory");
    SCHEDB();
    __builtin_amdgcn_s_setprio(1);
    MFMA4x2(a03, b01, 0, 0);
    __builtin_amdgcn_s_setprio(0);
    SBAR();
    // ---- P2: read a47 (8); stage B1(t+1); MFMA Q2 = a47 x b01
#pragma unroll
    for (int mi = 0; mi < 4; mi++){ a47[mi][0] = LDA8(mi + 4, 0); a47[mi][1] = LDA8(mi + 4, 1); }
    STAGE_B(t + 1, 1);
    SBAR();
    asm volatile("s_waitcnt lgkmcnt(0)" ::: "memory");
    SCHEDB();
    __builtin_amdgcn_s_setprio(1);
    MFMA4x2(a47, b01, 4, 0);
    __builtin_amdgcn_s_setprio(0);
    SBAR();
    // ---- P3: read b23 (4); stage A0(t+2) (As[bi] reads done at P2); MFMA Q3 = a03 x b23
#pragma unroll
    for (int ni = 0; ni < 2; ni++){ b23[ni][0] = LDB8(ni + 2, 0); b23[ni][1] = LDB8(ni + 2, 1); }
    STAGE_A(t + 2, 0);
    SBAR();
    asm volatile("s_waitcnt lgkmcnt(0)" ::: "memory");
    SCHEDB();
    __builtin_amdgcn_s_setprio(1);
    MFMA4x2(a03, b23, 0, 2);
    __builtin_amdgcn_s_setprio(0);
    SBAR();
    // ---- P4: stage A1(t+2); MFMA Q4 = a47 x b23; counted vmcnt(4)
    STAGE_A(t + 2, 1);
    SBAR();
    __builtin_amdgcn_s_setprio(1);
    MFMA4x2(a47, b23, 4, 2);
    __builtin_amdgcn_s_setprio(0);
    if (t + 2 < nt) asm volatile("s_waitcnt vmcnt(4)" ::: "memory");
    else            asm volatile("s_waitcnt vmcnt(0)" ::: "memory");
    SBAR();
  }
#undef GSTAGE
#undef STAGE_A
#undef STAGE_B
#undef LDA8
#undef LDB8
#undef MFMA4x2

#pragma unroll
  for (int mi = 0; mi < 8; mi++)
#pragma unroll
    for (int ni = 0; ni < 4; ni++)
#pragma unroll
      for (int r = 0; r < 4; r++){
        int row = m0 + wm * 128 + mi * 16 + l4 * 4 + r;
        int col = n0 + wn * 64 + ni * 16 + l15;
        long idx = (long)row * ldc + col;
        float v = acc[mi][ni][r];
        if (MODE == 0) Cb[idx] = f2bf(v);
        else           Cf[idx] = v + resid[idx];
      }
}

// ======== fused FFN13, balanced phases (256m x 128n): G = silu(A@W1t^T) * (A@W3t^T) ========
__global__ __launch_bounds__(512, 2) void ffn13_256(const unsigned short* __restrict__ A,
                                                    const unsigned short* __restrict__ B1t,
                                                    const unsigned short* __restrict__ B3t,
                                                    unsigned short* __restrict__ G,
                                                    int M, int N, int K){
  __shared__ alignas(16) unsigned short As[2][256 * 64];
  __shared__ alignas(16) unsigned short B1s[2][128 * 64];
  __shared__ alignas(16) unsigned short B3s[2][128 * 64];
  int m0 = blockIdx.y * 256, n0 = blockIdx.x * 128;
  int tid = threadIdx.x, w = tid >> 6, l = tid & 63;
  int wm = w >> 2, wn = w & 3;   // wave tile: 128m x 32n
  int l15 = l & 15, l4 = l >> 4;
  int sr8 = l >> 3, sl = l & 7;
  int nt = K / 64;

  f32x4 acc1[8][2], acc3[8][2];
#pragma unroll
  for (int i = 0; i < 8; i++)
#pragma unroll
    for (int j = 0; j < 2; j++){ acc1[i][j] = (f32x4){0.f,0.f,0.f,0.f}; acc3[i][j] = (f32x4){0.f,0.f,0.f,0.f}; }

#define GSTAGE(Gp, ld_, r0_, slab) { \
    _Pragma("unroll") \
    for (int r = 0; r < 2; r++){ \
      int row = (r * 8 + w) * 8 + sr8; \
      int cs = sl ^ (row & 7); \
      GLD16((Gp) + (long)((r0_) + row) * (ld_) + cs * 8, (slab) + (r * 8 + w) * 512); \
    } }
#define STAGE_A(tt, half) { int _t = (tt); if (_t < nt) GSTAGE(A + _t * 64, K, m0 + (half) * 128, &As[_t & 1][(half) * 8192]) }
#define STAGE_B1(tt) { int _t = (tt); if (_t < nt) GSTAGE(B1t + _t * 64, K, n0, &B1s[_t & 1][0]) }
#define STAGE_B3(tt) { int _t = (tt); if (_t < nt) GSTAGE(B3t + _t * 64, K, n0, &B3s[_t & 1][0]) }
#define LDA8(mi, ks) (*(const bf16x8*)(&As[bi][(wm * 128 + (mi) * 16 + l15) * 64 + (((ks) * 4 + l4) ^ (l15 & 7)) * 8]))
#define LDB18(ni, ks) (*(const bf16x8*)(&B1s[bi][(wn * 32 + (ni) * 16 + l15) * 64 + (((ks) * 4 + l4) ^ (l15 & 7)) * 8]))
#define LDB38(ni, ks) (*(const bf16x8*)(&B3s[bi][(wn * 32 + (ni) * 16 + l15) * 64 + (((ks) * 4 + l4) ^ (l15 & 7)) * 8]))
#define MFMA4x2(AF, BF, ACC, MOFF) { \
    _Pragma("unroll") \
    for (int mi = 0; mi < 4; mi++) \
      _Pragma("unroll") \
      for (int ni = 0; ni < 2; ni++) \
        _Pragma("unroll") \
        for (int ks = 0; ks < 2; ks++) \
          ACC[mi + (MOFF)][ni] = __builtin_amdgcn_mfma_f32_16x16x32_bf16(AF[mi][ks], BF[ni][ks], ACC[mi + (MOFF)][ni], 0, 0, 0); }

  // prologue: tile0 all pieces + tile1 A0,A1 (B1(1)/B3(1) issued at t=0 P1/P2)
  STAGE_A(0, 0); STAGE_A(0, 1); STAGE_B1(0); STAGE_B3(0);
  STAGE_A(1, 0); STAGE_A(1, 1);
  asm volatile("s_waitcnt vmcnt(4)" ::: "memory");
  __syncthreads();

  for (int t = 0; t < nt; t++){
    int bi = t & 1;
    bf16x8 a03[4][2], a47[4][2], b1f[2][2], b3f[2][2];
    // ---- P1: read a03 + b1f (12); stage B1(t+1); MFMA acc1 mi0-3
#pragma unroll
    for (int mi = 0; mi < 4; mi++){ a03[mi][0] = LDA8(mi, 0); a03[mi][1] = LDA8(mi, 1); }
#pragma unroll
    for (int ni = 0; ni < 2; ni++){ b1f[ni][0] = LDB18(ni, 0); b1f[ni][1] = LDB18(ni, 1); }
    STAGE_B1(t + 1);
    SBAR();
    asm volatile("s_waitcnt lgkmcnt(0)" ::: "memory");
    SCHEDB();
    __builtin_amdgcn_s_setprio(1);
    MFMA4x2(a03, b1f, acc1, 0);
    __builtin_amdgcn_s_setprio(0);
    SBAR();
    // ---- P2: read a47 (8); stage B3(t+1); MFMA acc1 mi4-7
#pragma unroll
    for (int mi = 0; mi < 4; mi++){ a47[mi][0] = LDA8(mi + 4, 0); a47[mi][1] = LDA8(mi + 4, 1); }
    STAGE_B3(t + 1);
    SBAR();
    asm volatile("s_waitcnt lgkmcnt(0)" ::: "memory");
    SCHEDB();
    __builtin_amdgcn_s_setprio(1);
    MFMA4x2(a47, b1f, acc1, 4);
    __builtin_amdgcn_s_setprio(0);
    SBAR();
    // ---- P3: read b3f (4); stage A0(t+2) (As[bi] reads done at P2); MFMA acc3 mi0-3
#pragma unroll
    for (int ni = 0; ni < 2; ni++){ b3f[ni][0] = LDB38(ni, 0); b3f[ni][1] = LDB38(ni, 1); }
    STAGE_A(t + 2, 0);
    SBAR();
    asm volatile("s_waitcnt lgkmcnt(0)" ::: "memory");
    SCHEDB();
    __builtin_amdgcn_s_setprio(1);
    MFMA4x2(a03, b3f, acc3, 0);
    __builtin_amdgcn_s_setprio(0);
    SBAR();
    // ---- P4: stage A1(t+2); MFMA acc3 mi4-7; counted vmcnt(4)
    STAGE_A(t + 2, 1);
    SBAR();
    __builtin_amdgcn_s_setprio(1);
    MFMA4x2(a47, b3f, acc3, 4);
    __builtin_amdgcn_s_setprio(0);
    if (t + 2 < nt) asm volatile("s_waitcnt vmcnt(4)" ::: "memory");
    else            asm volatile("s_waitcnt vmcnt(0)" ::: "memory");
    SBAR();
  }
#undef GSTAGE
#undef STAGE_A
#undef STAGE_B1
#undef STAGE_B3
#undef LDA8
#undef LDB18
#undef LDB38
#undef MFMA4x2

#pragma unroll
  for (int mi = 0; mi < 8; mi++)
#pragma unroll
    for (int ni = 0; ni < 2; ni++)
#pragma unroll
      for (int r = 0; r < 4; r++){
        int row = m0 + wm * 128 + mi * 16 + l4 * 4 + r;
        int col = n0 + wn * 32 + ni * 16 + l15;
        float a = acc1[mi][ni][r];
        float si = a * (1.f / (1.f + __expf(-a)));
        G[(long)row * N + col] = f2bf(si * acc3[mi][ni][r]);
      }
}

// ---------------- RoPE on packed qkv (q: cols 0-2047, k: cols 2048-4095); q scaled ----------------
__global__ __launch_bounds__(256) void rope_k(unsigned short* __restrict__ p,
                                              const float* __restrict__ cosT,
                                              const float* __restrict__ sinT,
                                              float qscale){
  long idx = (long)blockIdx.x * 256 + threadIdx.x; // (row, h, i)
  int i = (int)(idx & 63);
  long t = idx >> 6;
  int h = (int)(t & 15);
  long row = t >> 4;
  int s = (int)(row & (SEQV - 1));
  float c = cosT[s * 64 + i], sn = sinT[s * 64 + i];
  long base = row * LDP + h * HDV + 2 * i;
  unsigned pq = *(unsigned*)(p + base);
  float a = bf2f((unsigned short)(pq & 0xffff)), b = bf2f((unsigned short)(pq >> 16));
  float ra = (a * c - b * sn) * qscale, rb = (a * sn + b * c) * qscale;
  *(unsigned*)(p + base) = (unsigned)f2bf(ra) | ((unsigned)f2bf(rb) << 16);
  unsigned pk = *(unsigned*)(p + base + 2048);
  a = bf2f((unsigned short)(pk & 0xffff)); b = bf2f((unsigned short)(pk >> 16));
  ra = a * c - b * sn; rb = a * sn + b * c;
  *(unsigned*)(p + base + 2048) = (unsigned)f2bf(ra) | ((unsigned)f2bf(rb) << 16);
}

// ---------------- Flash attention (causal), 8 waves / 128 q-rows, dbuf, XOR-swizzled LDS ----------------
// packed: q cols [0,2048), k cols [2048,4096); o over q region. vt: [64 bh][128 d][2048 s].
__global__ __launch_bounds__(512) void attn_k(unsigned short* __restrict__ p,
                                              const unsigned short* __restrict__ vt){
  __shared__ alignas(16) unsigned short Ks[2][64 * 128]; // [key][d], slot ^= key&7
  __shared__ alignas(16) unsigned short Vs[2][128 * 64]; // [d][key], slot ^= d&7
  __shared__ alignas(16) unsigned short Ps[8][16 * 64];  // per-wave [qr][key], swizzled
  int qt = (gridDim.x - 1) - blockIdx.x;  // reversed: big blocks first
  int bh = blockIdx.y;
  int b = bh >> 4, h = bh & 15;
  int tid = threadIdx.x, w = tid >> 6, l = tid & 63;
  int l15 = l & 15, l4 = l >> 4;
  int qrow0 = qt * 128 + w * 16;
  long baseQ = (long)b * SEQV * LDP + (long)h * HDV;
  long baseV = (long)bh * HDV * SEQV;

  bf16x8 qf[4];
#pragma unroll
  for (int dc = 0; dc < 4; dc++)
    qf[dc] = *(const bf16x8*)(p + baseQ + (long)(qrow0 + l15) * LDP + dc * 32 + l4 * 8);

  f32x4 acc[8];
#pragma unroll
  for (int df = 0; df < 8; df++) acc[df] = (f32x4){0.f, 0.f, 0.f, 0.f};
  float mOld[4], lsum[4];
#pragma unroll
  for (int r = 0; r < 4; r++){ mOld[r] = -1e30f; lsum[r] = 0.f; }

  // 8 waves share staging: wave w stages K rows [w*8, w*8+8) and V rows [w*16, w*16+16)
#define ATTN_STAGE(buf, kt) {                                                       \
    int k0 = (kt) * 64;                                                             \
    _Pragma("unroll")                                                               \
    for (int i = 0; i < 2; i++){                                                    \
      int row = w * 8 + i * 4 + (l >> 4);                                           \
      int slot = (l & 15) ^ (row & 7);                                              \
      GLD16(p + baseQ + 2048 + (long)(k0 + row) * LDP + slot * 8,                   \
            Ks[buf] + (w * 8 + i * 4) * 128);                                       \
    }                                                                               \
    _Pragma("unroll")                                                               \
    for (int i = 0; i < 2; i++){                                                    \
      int row = w * 16 + i * 8 + (l >> 3);                                          \
      int slot = (l & 7) ^ (row & 7);                                               \
      GLD16(vt + baseV + (long)row * SEQV + k0 + slot * 8,                          \
            Vs[buf] + (w * 16 + i * 8) * 64);                                       \
    } }

  int ntile = 2 * (qt + 1);
  ATTN_STAGE(0, 0);
  asm volatile("s_waitcnt vmcnt(0)" ::: "memory");
  __syncthreads();
  int cur = 0;
  for (int tki = 0; tki < ntile; tki++){
    int k0 = tki * 64;
    if (tki + 1 < ntile) ATTN_STAGE(cur ^ 1, tki + 1);

    float s[4][4];
    __builtin_amdgcn_s_setprio(1);
#pragma unroll
    for (int kf = 0; kf < 4; kf++){
      f32x4 sf = (f32x4){0.f, 0.f, 0.f, 0.f};
#pragma unroll
      for (int dc = 0; dc < 4; dc++){
        bf16x8 kb = *(const bf16x8*)(Ks[cur] + (kf * 16 + l15) * 128 + (((dc * 4 + l4) ^ (l15 & 7)) * 8));
        sf = __builtin_amdgcn_mfma_f32_16x16x32_bf16(qf[dc], kb, sf, 0, 0, 0);
      }
      int key = k0 + kf * 16 + l15;
#pragma unroll
      for (int r = 0; r < 4; r++){
        int rowi = qrow0 + l4 * 4 + r;
        s[kf][r] = (key <= rowi) ? sf[r] : -1e30f;
      }
    }
    __builtin_amdgcn_s_setprio(0);
    float scale[4];
#pragma unroll
    for (int r = 0; r < 4; r++){
      float vmax = fmaxf(fmaxf(s[0][r], s[1][r]), fmaxf(s[2][r], s[3][r]));
      for (int mm = 8; mm; mm >>= 1) vmax = fmaxf(vmax, __shfl_xor(vmax, mm));
      float mNew = fmaxf(mOld[r], vmax);
      scale[r] = __expf(mOld[r] - mNew);
      float ps = 0.f;
#pragma unroll
      for (int kf = 0; kf < 4; kf++){
        float pp = __expf(s[kf][r] - mNew);
        s[kf][r] = pp;
        ps += pp;
      }
      for (int mm = 8; mm; mm >>= 1) ps += __shfl_xor(ps, mm);
      lsum[r] = lsum[r] * scale[r] + ps;
      mOld[r] = mNew;
    }
#pragma unroll
    for (int df = 0; df < 8; df++)
#pragma unroll
      for (int r = 0; r < 4; r++) acc[df][r] *= scale[r];
#pragma unroll
    for (int kf = 0; kf < 4; kf++)
#pragma unroll
      for (int r = 0; r < 4; r++){
        int row = l4 * 4 + r;
        int sidx = row * 64 + (((((kf * 16 + l15) * 2)) ^ ((row & 7) << 4)) >> 1);
        Ps[w][sidx] = f2bf(s[kf][r]);
      }
    __builtin_amdgcn_s_setprio(1);
#pragma unroll
    for (int kc = 0; kc < 2; kc++){
      bf16x8 pa = *(const bf16x8*)(Ps[w] + l15 * 64 + (((kc * 64 + l4 * 16) ^ ((l15 & 7) << 4)) >> 1));
#pragma unroll
      for (int df = 0; df < 8; df++){
        bf16x8 vb = *(const bf16x8*)(Vs[cur] + (df * 16 + l15) * 64 + (((kc * 4 + l4) ^ (l15 & 7)) * 8));
        acc[df] = __builtin_amdgcn_mfma_f32_16x16x32_bf16(pa, vb, acc[df], 0, 0, 0);
      }
    }
    __builtin_amdgcn_s_setprio(0);
    asm volatile("s_waitcnt vmcnt(0)" ::: "memory");
    __syncthreads();
    cur ^= 1;
  }
#pragma unroll
  for (int df = 0; df < 8; df++)
#pragma unroll
    for (int r = 0; r < 4; r++){
      int rows = qrow0 + l4 * 4 + r;
      p[baseQ + (long)rows * LDP + df * 16 + l15] = f2bf(acc[df][r] / lsum[r]);
    }
#undef ATTN_STAGE
}

extern "C" void kernel_launch(void* const* d_in, const int* in_sizes, int n_in,
                              void* d_out, int out_size, void* d_ws, size_t ws_size,
                              hipStream_t stream){
  const float* x    = (const float*)d_in[0];
  const float* wq   = (const float*)d_in[1];
  const float* wk   = (const float*)d_in[2];
  const float* wv   = (const float*)d_in[3];
  const float* wo   = (const float*)d_in[4];
  const float* w1   = (const float*)d_in[5];
  const float* w2   = (const float*)d_in[6]; // (HID, DIM)
  const float* w3   = (const float*)d_in[7];
  const float* anw  = (const float*)d_in[8];
  const float* fnw  = (const float*)d_in[9];
  const float* fcos = (const float*)d_in[10];
  const float* fsin = (const float*)d_in[11];

  char* ws = (char*)d_ws;
  size_t off = 0;
  auto alloc = [&](size_t bytes) -> void* {
    void* p = ws + off;
    off += (bytes + 255) & ~(size_t)255;
    return p;
  };
  const size_t SQ = (size_t)DIMV * DIMV * 2;      // 8 MB
  const size_t SW = (size_t)DIMV * HIDV * 2;      // 22 MB
  const size_t SA = (size_t)NROWS * DIMV * 2;     // 32 MB
  const size_t SP = (size_t)NROWS * LDP * 2;      // 96 MB packed qkv

  unsigned short* wqT = (unsigned short*)alloc(SQ);   // wqT|wkT|wvT contiguous: Bt rows 0..6143
  unsigned short* wkT = (unsigned short*)alloc(SQ);
  unsigned short* wvT = (unsigned short*)alloc(SQ);
  unsigned short* woT = (unsigned short*)alloc(SQ);
  unsigned short* w1T = (unsigned short*)alloc(SW);
  unsigned short* w3T = (unsigned short*)alloc(SW);
  unsigned short* w2T = (unsigned short*)alloc(SW);
  unsigned short* hn  = (unsigned short*)alloc(SA);   // attn-norm; reused as vt during attn; rewritten as ffn-norm
  unsigned short* pk  = (unsigned short*)alloc(SP);   // packed [row][q|k|v]; later reused as g
  unsigned short* vtb = hn;                           // vt[64 bh][128 d][2048 s] == 32 MB
  unsigned short* g   = pk;                           // FFN gate (88 MB) reuses packed (96 MB)
  float* hf = (float*)d_out;                          // h = x + attn (f32) lives in d_out
  (void)ws_size; (void)in_sizes; (void)n_in; (void)out_size;
  (void)wkT; (void)wvT;

  dim3 tb(32, 8);
  // four DIM x DIM weights in one dispatch; w1/w3 in one; w2 alone
  transpose_cast4<<<dim3(DIMV/32, DIMV/32, 4), tb, 0, stream>>>(wq, wk, wv, wo, wqT, wkT, wvT, woT, DIMV, DIMV);
  transpose_cast4<<<dim3(HIDV/32, DIMV/32, 2), tb, 0, stream>>>(w1, w3, nullptr, nullptr, w1T, w3T, nullptr, nullptr, DIMV, HIDV);
  transpose_cast4<<<dim3(DIMV/32, HIDV/32, 1), tb, 0, stream>>>(w2, nullptr, nullptr, nullptr, w2T, nullptr, nullptr, nullptr, HIDV, DIMV);

  rmsnorm_k<<<NROWS, 256, 0, stream>>>(x, anw, hn);

  // fused QKV: packed[row][6144] = hn @ [wq|wk|wv]
  gemm256<0><<<dim3(LDP/256, NROWS/256), 512, 0, stream>>>(hn, DIMV, wqT, pk, nullptr, nullptr, LDP, NROWS, LDP, DIMV);

  rope_k<<<(NROWS * NHV * 64) / 256, 256, 0, stream>>>(pk, fcos, fsin, 0.08838834764831845f);

  transpose_v<<<dim3(SEQV/32, HDV/32, 4 * NHV), tb, 0, stream>>>(pk, vtb);

  attn_k<<<dim3(SEQV/128, 4 * NHV), 512, 0, stream>>>(pk, vtb);

  // h = attn @ wo + x
  gemm256<1><<<dim3(DIMV/256, NROWS/256), 512, 0, stream>>>(pk, LDP, woT, nullptr, hf, x, DIMV, NROWS, DIMV, DIMV);

  rmsnorm_k<<<NROWS, 256, 0, stream>>>(hf, fnw, hn);

  ffn13_256<<<dim3(HIDV/128, NROWS/256), 512, 0, stream>>>(hn, w1T, w3T, g, NROWS, HIDV, DIMV);

  gemm256<1><<<dim3(DIMV/256, NROWS/256), 512, 0, stream>>>(g, HIDV, w2T, nullptr, hf, (const float*)hf, DIMV, NROWS, DIMV, HIDV);
}